// Round 10
// baseline (353.383 us; speedup 1.0000x reference)
//
#include <hip/hip_runtime.h>
#include <hip/hip_bf16.h>

#define NROWS 16384      // total feats rows
#define NHALF 8192       // normal rows
#define KDIM  256
#define TMARGIN 100.0f

#define BM 128                              // rows per block (LDS-staged)
#define NROWBLK (NHALF / BM)                // 64
#define NCOLSPLIT 8                         // col panels == XCDs (bid&7 pins panel to XCD)
#define COLS_PER_SPLIT (NROWS / NCOLSPLIT)  // 2048
#define CC_ITERS (COLS_PER_SPLIT / 128)     // 16 col-chunks of 128 per block

typedef __bf16 bf16x8 __attribute__((ext_vector_type(8)));
typedef __bf16 bf16x4 __attribute__((ext_vector_type(4)));
typedef float  f32x16 __attribute__((ext_vector_type(16)));

// Static device scratch; fully rewritten every call.
__device__ __bf16 g_bf[NROWS * KDIM];            // bf16 copy of feats
__device__ float  g_sq[NROWS];                   // row squared norms
__device__ float  g_part[NROWBLK * NROWS];       // per-col partials of (sqa - 2c), 4 MB
__device__ float  g_colres[NROWS];               // per-col final (sqrt'd / hinged)

// ---------------- Kernel 1: fp32 -> bf16 + row norms ----------------
__global__ __launch_bounds__(256) void prep_kernel(const float* __restrict__ feats) {
    int w    = threadIdx.x >> 6;
    int lane = threadIdx.x & 63;
    int row  = blockIdx.x * 4 + w;

    const float* rp = feats + (size_t)row * KDIM + lane * 4;
    float4 v = *(const float4*)rp;

    bf16x4 b;
    b[0] = (__bf16)v.x; b[1] = (__bf16)v.y; b[2] = (__bf16)v.z; b[3] = (__bf16)v.w;
    *(bf16x4*)(g_bf + (size_t)row * KDIM + lane * 4) = b;

    float sq = v.x*v.x + v.y*v.y + v.z*v.z + v.w*v.w;
    #pragma unroll
    for (int off = 32; off > 0; off >>= 1) sq += __shfl_xor(sq, off);
    if (lane == 0) g_sq[row] = sq;
}

// ---------------- Kernel 2: A-in-LDS distance GEMM (32x32x16) + column fold ----------
// Block = 4 waves; EACH wave covers all 128 rows x its own 32 cols (no duplicate B).
// A tile (128x256) staged once in LDS (XOR swizzle bits 4-6); barrier-free main loop.
// Per k-step (k=16): 4 ds_read_b128 (A) + 1 global b128 (B) + 4 MFMA 32x32x16.
// B prefetch 4 steps deep (4 buffers); A prefetch 1 step deep (2 buffers).
__global__ __launch_bounds__(256, 2) void dist_kernel() {
    __shared__ __align__(16) char smem[BM * KDIM * 2];   // 64 KB

    int tid  = threadIdx.x;
    int w    = tid >> 6;        // wave -> 32-col sub-panel
    int lane = tid & 63;
    int l31  = lane & 31;
    int hh   = lane >> 5;       // k-half

    int bid      = blockIdx.x;
    int colsplit = bid & (NCOLSPLIT - 1);   // XCD-pinned B panel (2048 cols)
    int rowblk   = bid >> 3;                // 0..63
    bool minmode = colsplit >= (NCOLSPLIT / 2);

    // ---- stage A tile into LDS (byte ^= (row&7)<<4 within row) ----
    {
        const __bf16* src = g_bf + (size_t)rowblk * BM * KDIM;
        #pragma unroll
        for (int i = 0; i < 16; ++i) {
            int chunk = tid + i * 256;          // 0..4095 16B-chunks
            int row = chunk >> 5;
            int kc  = chunk & 31;
            bf16x8 v = *(const bf16x8*)(src + row * KDIM + kc * 8);
            int dst = row * 512 + ((kc * 16) ^ ((row & 7) << 4));
            *(bf16x8*)(smem + dst) = v;
        }
    }
    __syncthreads();

    // LDS read addr(m',s) = m'*16384 + l31*512 + ((s*32 | hh*16) ^ ((lane&7)<<4))
    //                     = m'*16384 + base_l + ((s*32)^q) + p   (disjoint bit fields)
    int xorf   = (lane & 7) << 4;
    int base_l = l31 * 512;
    int q      = xorf & 0x60;
    int p      = (hh * 16) ^ (xorf & 0x10);

    // preload sq for the C/D rows this lane owns (row = mp*32 + (r&3)+8*(r>>2)+4*hh)
    int rowglob = rowblk * BM;
    float sqv[4][16];
    #pragma unroll
    for (int mp = 0; mp < 4; ++mp)
        #pragma unroll
        for (int r = 0; r < 16; ++r)
            sqv[mp][r] = g_sq[rowglob + mp * 32 + 4 * hh + (r & 3) + 8 * (r >> 2)];

    // per-lane B pointer: col = colsplit*2048 + w*32 + l31, k-offset hh*8
    const __bf16* bpanel = g_bf
        + (size_t)(colsplit * COLS_PER_SPLIT + w * 32 + l31) * KDIM + hh * 8;

    float init = minmode ? 3.0e38f : -3.0e38f;

    bf16x8 A_[2][4], B_[4];

#define LOADA(SLOT, S)                                                         \
    {                                                                          \
        int a_ = base_l + (((S) * 32) ^ q) + p;                                \
        A_[SLOT][0] = *(const bf16x8*)(smem + a_);                             \
        A_[SLOT][1] = *(const bf16x8*)(smem + a_ + 16384);                     \
        A_[SLOT][2] = *(const bf16x8*)(smem + a_ + 32768);                     \
        A_[SLOT][3] = *(const bf16x8*)(smem + a_ + 49152);                     \
    }
#define LOADB(SLOT, CC, S)                                                     \
    B_[SLOT] = *(const bf16x8*)(bpanel + (size_t)(CC) * (128 * KDIM) + (S) * 16);

    // prologue
    LOADA(0, 0);
    LOADB(0, 0, 0); LOADB(1, 0, 1); LOADB(2, 0, 2); LOADB(3, 0, 3);

    for (int cc = 0; cc < CC_ITERS; ++cc) {
        int ccn = (cc + 1 < CC_ITERS) ? cc + 1 : cc;   // clamped (dead tail loads)

        f32x16 acc[4];
        #pragma unroll
        for (int mp = 0; mp < 4; ++mp)
            #pragma unroll
            for (int j = 0; j < 16; ++j) acc[mp][j] = 0.f;

        #pragma unroll
        for (int s = 0; s < 16; ++s) {
            LOADA((s + 1) & 1, (s + 1) & 15);          // A for next step (wraps to next cc)
            #pragma unroll
            for (int mp = 0; mp < 4; ++mp)
                acc[mp] = __builtin_amdgcn_mfma_f32_32x32x16_bf16(
                    A_[s & 1][mp], B_[s & 3], acc[mp], 0, 0, 0);
            if (s < 12) { LOADB(s & 3, cc,  s + 4);  } // B 4 steps ahead
            else        { LOADB(s & 3, ccn, s - 12); } // next cc's prologue
        }

        // fold t = sq_row - 2c into per-column running max/min
        float m_run = init;
        #pragma unroll
        for (int mp = 0; mp < 4; ++mp)
            #pragma unroll
            for (int r = 0; r < 16; ++r) {
                float t = sqv[mp][r] - 2.0f * acc[mp][r];
                m_run = minmode ? fminf(m_run, t) : fmaxf(m_run, t);
            }
        float o = __shfl_xor(m_run, 32);               // other k-half = other row set
        m_run = minmode ? fminf(m_run, o) : fmaxf(m_run, o);

        if (lane < 32) {
            int colw = colsplit * COLS_PER_SPLIT + cc * 128 + w * 32;
            g_part[(size_t)rowblk * NROWS + colw + l31] = m_run;
        }
    }
#undef LOADA
#undef LOADB
}

// ---------------- Kernel 3: per-column reduce over 64 partials ----------------
__global__ __launch_bounds__(256) void finish1_kernel() {
    int col = blockIdx.x * 256 + threadIdx.x;        // grid 64 -> 16384 cols
    bool mn = col >= NHALF;
    float m = mn ? 3.0e38f : -3.0e38f;
    for (int p = 0; p < NROWBLK; ++p) {
        float v = g_part[(size_t)p * NROWS + col];   // coalesced across threads
        m = mn ? fminf(m, v) : fmaxf(m, v);
    }
    float d = sqrtf(fmaxf(m + g_sq[col], 0.f));
    g_colres[col] = mn ? fmaxf(TMARGIN - d, 0.f) : d;
}

// ---------------- Kernel 4: sum columns, scalar out ----------------
__global__ __launch_bounds__(256) void finish2_kernel(float* __restrict__ out) {
    int tid = threadIdx.x;
    float s1 = 0.f, s2 = 0.f;
    for (int j = tid; j < NROWS; j += 256) {
        float v = g_colres[j];
        if (j < NHALF) s1 += v; else s2 += v;
    }
    #pragma unroll
    for (int off = 32; off > 0; off >>= 1) {
        s1 += __shfl_xor(s1, off);
        s2 += __shfl_xor(s2, off);
    }
    __shared__ float r1[4], r2[4];
    int w = tid >> 6, lane = tid & 63;
    if (lane == 0) { r1[w] = s1; r2[w] = s2; }
    __syncthreads();
    if (tid == 0) {
        float a = r1[0] + r1[1] + r1[2] + r1[3];
        float b = r2[0] + r2[1] + r2[2] + r2[3];
        out[0] = a / (float)NHALF + b / (float)NHALF;
    }
}

extern "C" void kernel_launch(void* const* d_in, const int* in_sizes, int n_in,
                              void* d_out, int out_size, void* d_ws, size_t ws_size,
                              hipStream_t stream) {
    const float* feats = (const float*)d_in[0];
    float* out = (float*)d_out;
    hipLaunchKernelGGL(prep_kernel,    dim3(NROWS / 4),           dim3(256), 0, stream, feats);
    hipLaunchKernelGGL(dist_kernel,    dim3(NROWBLK * NCOLSPLIT), dim3(256), 0, stream);
    hipLaunchKernelGGL(finish1_kernel, dim3(NROWS / 256),         dim3(256), 0, stream);
    hipLaunchKernelGGL(finish2_kernel, dim3(1),                   dim3(256), 0, stream, out);
}

// Round 11
// 350.969 us; speedup vs baseline: 1.0069x; 1.0069x over previous
//
#include <hip/hip_runtime.h>
#include <hip/hip_bf16.h>

#define NROWS 16384      // total feats rows
#define NHALF 8192       // normal rows
#define KDIM  256
#define TMARGIN 100.0f

#define BM 128                              // rows per block (LDS-staged)
#define NROWBLK (NHALF / BM)                // 64
#define NCOLSPLIT 8                         // col panels == XCDs (bid&7 pins panel to XCD)
#define COLS_PER_SPLIT (NROWS / NCOLSPLIT)  // 2048
#define CC_ITERS (COLS_PER_SPLIT / 128)     // 16 col-chunks of 128 per block

typedef __bf16 bf16x8 __attribute__((ext_vector_type(8)));
typedef __bf16 bf16x4 __attribute__((ext_vector_type(4)));
typedef float  f32x4  __attribute__((ext_vector_type(4)));
typedef float  f32x16 __attribute__((ext_vector_type(16)));

// Static device scratch; fully rewritten every call.
__device__ __bf16 g_bf[NROWS * KDIM];            // bf16 copy of feats
__device__ float  g_sq[NROWS];                   // row squared norms
__device__ float  g_part[NROWBLK * NROWS];       // per-col partials of (sqa - 2c), 4 MB
__device__ float  g_colres[NROWS];               // per-col final (sqrt'd / hinged)

// ---------------- Kernel 1: fp32 -> bf16 + row norms ----------------
__global__ __launch_bounds__(256) void prep_kernel(const float* __restrict__ feats) {
    int w    = threadIdx.x >> 6;
    int lane = threadIdx.x & 63;
    int row  = blockIdx.x * 4 + w;

    const float* rp = feats + (size_t)row * KDIM + lane * 4;
    float4 v = *(const float4*)rp;

    bf16x4 b;
    b[0] = (__bf16)v.x; b[1] = (__bf16)v.y; b[2] = (__bf16)v.z; b[3] = (__bf16)v.w;
    *(bf16x4*)(g_bf + (size_t)row * KDIM + lane * 4) = b;

    float sq = v.x*v.x + v.y*v.y + v.z*v.z + v.w*v.w;
    #pragma unroll
    for (int off = 32; off > 0; off >>= 1) sq += __shfl_xor(sq, off);
    if (lane == 0) g_sq[row] = sq;
}

// ---------------- Kernel 2: A-in-LDS distance GEMM (32x32x16) + column fold ----------
// Block = 4 waves; EACH wave covers all 128 rows x its own 32 cols (no duplicate B).
// A tile (128x256) staged once in LDS (XOR swizzle bits 4-6); barrier-free main loop.
// Per k-step (k=16): 4 ds_read_b128 (A) + 1 global b128 (B) + 4 MFMA 32x32x16.
// B prefetch 4 steps deep (4 buffers); A prefetch 1 step deep (2 buffers).
// Row norms kept in a 512 B LDS slice (NOT registers -- R9's sqv table spilled).
__global__ __launch_bounds__(256, 2) void dist_kernel() {
    __shared__ __align__(16) char smem[BM * KDIM * 2 + BM * 4];  // 64 KB A + 512 B sq
    float* sq_lds = (float*)(smem + BM * KDIM * 2);

    int tid  = threadIdx.x;
    int w    = tid >> 6;        // wave -> 32-col sub-panel
    int lane = tid & 63;
    int l31  = lane & 31;
    int hh   = lane >> 5;       // k-half

    int bid      = blockIdx.x;
    int colsplit = bid & (NCOLSPLIT - 1);   // XCD-pinned B panel (2048 cols)
    int rowblk   = bid >> 3;                // 0..63
    bool minmode = colsplit >= (NCOLSPLIT / 2);

    // ---- stage A tile into LDS (byte ^= (row&7)<<4 within row) + sq slice ----
    {
        const __bf16* src = g_bf + (size_t)rowblk * BM * KDIM;
        #pragma unroll
        for (int i = 0; i < 16; ++i) {
            int chunk = tid + i * 256;          // 0..4095 16B-chunks
            int row = chunk >> 5;
            int kc  = chunk & 31;
            bf16x8 v = *(const bf16x8*)(src + row * KDIM + kc * 8);
            int dst = row * 512 + ((kc * 16) ^ ((row & 7) << 4));
            *(bf16x8*)(smem + dst) = v;
        }
        if (tid < BM) sq_lds[tid] = g_sq[rowblk * BM + tid];
    }
    __syncthreads();

    // LDS read addr(mp,s) = mp*16384 + l31*512 + ((s*32 | hh*16) ^ ((lane&7)<<4))
    //                     = mp*16384 + base_l + ((s*32)^q) + p   (disjoint bit fields)
    int xorf   = (lane & 7) << 4;
    int base_l = l31 * 512;
    int q      = xorf & 0x60;
    int p      = (hh * 16) ^ (xorf & 0x10);

    // per-lane B pointer: col = colsplit*2048 + w*32 + l31, k-offset hh*8
    const __bf16* bpanel = g_bf
        + (size_t)(colsplit * COLS_PER_SPLIT + w * 32 + l31) * KDIM + hh * 8;

    float init = minmode ? 3.0e38f : -3.0e38f;

    bf16x8 A_[2][4], B_[4];

#define LOADA(SLOT, S)                                                         \
    {                                                                          \
        int a_ = base_l + (((S) * 32) ^ q) + p;                                \
        A_[SLOT][0] = *(const bf16x8*)(smem + a_);                             \
        A_[SLOT][1] = *(const bf16x8*)(smem + a_ + 16384);                     \
        A_[SLOT][2] = *(const bf16x8*)(smem + a_ + 32768);                     \
        A_[SLOT][3] = *(const bf16x8*)(smem + a_ + 49152);                     \
    }
#define LOADB(SLOT, CC, S)                                                     \
    B_[SLOT] = *(const bf16x8*)(bpanel + (size_t)(CC) * (128 * KDIM) + (S) * 16);

    // prologue
    LOADA(0, 0);
    LOADB(0, 0, 0); LOADB(1, 0, 1); LOADB(2, 0, 2); LOADB(3, 0, 3);

    for (int cc = 0; cc < CC_ITERS; ++cc) {
        int ccn = (cc + 1 < CC_ITERS) ? cc + 1 : cc;   // clamped (dead tail loads)

        f32x16 acc[4];
        #pragma unroll
        for (int mp = 0; mp < 4; ++mp)
            #pragma unroll
            for (int j = 0; j < 16; ++j) acc[mp][j] = 0.f;

        #pragma unroll
        for (int s = 0; s < 16; ++s) {
            LOADA((s + 1) & 1, (s + 1) & 15);          // A for next step (wraps)
            #pragma unroll
            for (int mp = 0; mp < 4; ++mp)
                acc[mp] = __builtin_amdgcn_mfma_f32_32x32x16_bf16(
                    A_[s & 1][mp], B_[s & 3], acc[mp], 0, 0, 0);
            if (s < 12) { LOADB(s & 3, cc,  s + 4);  } // B 4 steps ahead
            else        { LOADB(s & 3, ccn, s - 12); } // next cc's prologue
        }

        // fold t = sq_row - 2c into per-column running max/min.
        // C/D row = mp*32 + 4*hh + (r&3) + 8*(r>>2); rows for fixed (r>>2) are
        // consecutive -> read sq 4-at-a-time from LDS (wave-broadcast, no VGPR table).
        float m_run = init;
        #pragma unroll
        for (int mp = 0; mp < 4; ++mp) {
            #pragma unroll
            for (int rq = 0; rq < 4; ++rq) {
                f32x4 s4 = *(const f32x4*)(sq_lds + mp * 32 + 4 * hh + 8 * rq);
                #pragma unroll
                for (int j = 0; j < 4; ++j) {
                    float t = s4[j] - 2.0f * acc[mp][rq * 4 + j];
                    m_run = minmode ? fminf(m_run, t) : fmaxf(m_run, t);
                }
            }
        }
        float o = __shfl_xor(m_run, 32);               // other k-half = other row set
        m_run = minmode ? fminf(m_run, o) : fmaxf(m_run, o);

        if (lane < 32) {
            int colw = colsplit * COLS_PER_SPLIT + cc * 128 + w * 32;
            g_part[(size_t)rowblk * NROWS + colw + l31] = m_run;
        }
    }
#undef LOADA
#undef LOADB
}

// ---------------- Kernel 3: per-column reduce over 64 partials ----------------
__global__ __launch_bounds__(256) void finish1_kernel() {
    int col = blockIdx.x * 256 + threadIdx.x;        // grid 64 -> 16384 cols
    bool mn = col >= NHALF;
    float m = mn ? 3.0e38f : -3.0e38f;
    for (int p = 0; p < NROWBLK; ++p) {
        float v = g_part[(size_t)p * NROWS + col];   // coalesced across threads
        m = mn ? fminf(m, v) : fmaxf(m, v);
    }
    float d = sqrtf(fmaxf(m + g_sq[col], 0.f));
    g_colres[col] = mn ? fmaxf(TMARGIN - d, 0.f) : d;
}

// ---------------- Kernel 4: sum columns, scalar out ----------------
__global__ __launch_bounds__(256) void finish2_kernel(float* __restrict__ out) {
    int tid = threadIdx.x;
    float s1 = 0.f, s2 = 0.f;
    for (int j = tid; j < NROWS; j += 256) {
        float v = g_colres[j];
        if (j < NHALF) s1 += v; else s2 += v;
    }
    #pragma unroll
    for (int off = 32; off > 0; off >>= 1) {
        s1 += __shfl_xor(s1, off);
        s2 += __shfl_xor(s2, off);
    }
    __shared__ float r1[4], r2[4];
    int w = tid >> 6, lane = tid & 63;
    if (lane == 0) { r1[w] = s1; r2[w] = s2; }
    __syncthreads();
    if (tid == 0) {
        float a = r1[0] + r1[1] + r1[2] + r1[3];
        float b = r2[0] + r2[1] + r2[2] + r2[3];
        out[0] = a / (float)NHALF + b / (float)NHALF;
    }
}

extern "C" void kernel_launch(void* const* d_in, const int* in_sizes, int n_in,
                              void* d_out, int out_size, void* d_ws, size_t ws_size,
                              hipStream_t stream) {
    const float* feats = (const float*)d_in[0];
    float* out = (float*)d_out;
    hipLaunchKernelGGL(prep_kernel,    dim3(NROWS / 4),           dim3(256), 0, stream, feats);
    hipLaunchKernelGGL(dist_kernel,    dim3(NROWBLK * NCOLSPLIT), dim3(256), 0, stream);
    hipLaunchKernelGGL(finish1_kernel, dim3(NROWS / 256),         dim3(256), 0, stream);
    hipLaunchKernelGGL(finish2_kernel, dim3(1),                   dim3(256), 0, stream, out);
}

// Round 15
// 185.243 us; speedup vs baseline: 1.9077x; 1.8946x over previous
//
#include <hip/hip_runtime.h>
#include <hip/hip_bf16.h>

#define NROWS 16384      // total feats rows
#define NHALF 8192       // normal rows
#define KDIM  256
#define TMARGIN 100.0f

#define BM 128                              // rows per block (LDS-staged)
#define NROWBLK (NHALF / BM)                // 64
#define NCOLSPLIT 8                         // col panels == XCDs (bid&7 pins panel to XCD)
#define COLS_PER_SPLIT (NROWS / NCOLSPLIT)  // 2048
#define CCW 64                              // cols per LDS chunk
#define CC_ITERS (COLS_PER_SPLIT / CCW)     // 32

typedef __bf16 bf16x8 __attribute__((ext_vector_type(8)));
typedef __bf16 bf16x4 __attribute__((ext_vector_type(4)));
typedef float  f32x4  __attribute__((ext_vector_type(4)));
typedef float  f32x16 __attribute__((ext_vector_type(16)));

// Static device scratch; fully rewritten every call.
__device__ __bf16 g_bf[NROWS * KDIM];            // bf16 copy of feats
__device__ float  g_sq[NROWS];                   // row squared norms
__device__ float  g_part[NROWBLK * NROWS];       // per-col partials of (sqa - 2c), 4 MB
__device__ float  g_colres[NROWS];               // per-col final (sqrt'd / hinged)

// ---------------- Kernel 1: fp32 -> bf16 + row norms ----------------
__global__ __launch_bounds__(256) void prep_kernel(const float* __restrict__ feats) {
    int w    = threadIdx.x >> 6;
    int lane = threadIdx.x & 63;
    int row  = blockIdx.x * 4 + w;

    const float* rp = feats + (size_t)row * KDIM + lane * 4;
    float4 v = *(const float4*)rp;

    bf16x4 b;
    b[0] = (__bf16)v.x; b[1] = (__bf16)v.y; b[2] = (__bf16)v.z; b[3] = (__bf16)v.w;
    *(bf16x4*)(g_bf + (size_t)row * KDIM + lane * 4) = b;

    float sq = v.x*v.x + v.y*v.y + v.z*v.z + v.w*v.w;
    #pragma unroll
    for (int off = 32; off > 0; off >>= 1) sq += __shfl_xor(sq, off);
    if (lane == 0) g_sq[row] = sq;
}

// ---------------- Kernel 2: A+B in LDS, 32x32x16 MFMA, column fold ----------------
// 512 thr = 8 waves = 4 rowgroups x 2 colgroups; each wave one 32x32 output tile.
// A tile 128x256 (64 KB) staged once, XOR-swizzled (byte ^= (row&7)<<4).
// B: 64-col chunks double-buffered (2 x 32 KB), staged via global_load_lds with
// PRE-SWIZZLED global source + LINEAR LDS dest; ds_read applies the same XOR.
// One __syncthreads per chunk drains the async staging + publishes fold partials.
__global__ __launch_bounds__(512, 1) void dist_kernel() {
    __shared__ __align__(16) char smem[133632];
    char*  bufA   = smem;                        // 64 KB A tile
    char*  bufB   = smem + 65536;                // 2 x 32 KB B chunks
    float* sq_lds = (float*)(smem + 131072);     // 128 row norms
    float* pbuf   = (float*)(smem + 131584);     // [2][4 rg][64 col] partials

    int tid  = threadIdx.x;
    int w    = tid >> 6;
    int lane = tid & 63;
    int l31  = lane & 31;
    int hh   = lane >> 5;
    int rg   = w & 3;           // rowgroup (32 rows)
    int cg   = w >> 2;          // colgroup (32 cols)

    int bid      = blockIdx.x;
    int colsplit = bid & (NCOLSPLIT - 1);   // XCD-pinned 2048-col B panel
    int rowblk   = bid >> 3;                // 0..63
    bool minmode = colsplit >= (NCOLSPLIT / 2);

    // ---- stage A tile (swizzled write) + sq slice ----
    {
        const __bf16* src = g_bf + (size_t)rowblk * BM * KDIM;
        #pragma unroll
        for (int i = 0; i < 8; ++i) {
            int chunk = tid + i * 512;          // 0..4095 16B-chunks
            int row = chunk >> 5;
            int kc  = chunk & 31;
            bf16x8 v = *(const bf16x8*)(src + row * KDIM + kc * 8);
            *(bf16x8*)(bufA + row * 512 + ((kc * 16) ^ ((row & 7) << 4))) = v;
        }
        if (tid < BM) sq_lds[tid] = g_sq[rowblk * BM + tid];
    }

    const char* gB = (const char*)g_bf;
    size_t panelbase = (size_t)colsplit * COLS_PER_SPLIT * (KDIM * 2);

    // Stage one 64-col chunk: linear LDS dest (wave base + lane*16), source address
    // inverse-swizzled so that swizzled ds_read returns the right bytes.
#define STAGE_B(BS, CCV)                                                        \
    {                                                                           \
        _Pragma("unroll")                                                       \
        for (int c = 0; c < 4; ++c) {                                           \
            int wbase = w * 4096 + c * 1024;                                    \
            int colw  = (wbase >> 9) + (lane >> 5);                             \
            int off   = (lane & 31) * 16;                                       \
            const void* gp = gB + panelbase                                     \
                + (size_t)((CCV) * CCW + colw) * 512                            \
                + (off ^ ((colw & 7) << 4));                                    \
            void* lp = bufB + (BS) * 32768 + wbase;                             \
            __builtin_amdgcn_global_load_lds(                                   \
                (const __attribute__((address_space(1))) void*)gp,              \
                (__attribute__((address_space(3))) void*)lp, 16, 0, 0);         \
        }                                                                       \
    }

    STAGE_B(0, 0);
    __syncthreads();   // A tile + sq + first B chunk ready (drains vmcnt)

    int swz = (l31 & 7) << 4;
    int qa  = swz & 0x60;
    int pa  = (hh * 16) ^ (swz & 0x10);
    int aoff = (rg * 32 + l31) * 512 + pa;      // A frag base (row = rg*32+l31)
    int boff = (cg * 32 + l31) * 512 + pa;      // B frag base (col = cg*32+l31)

    float init = minmode ? 3.0e38f : -3.0e38f;
    int cur = 0;

    #pragma unroll 1
    for (int cc = 0; cc < CC_ITERS; ++cc) {
        if (cc + 1 < CC_ITERS) STAGE_B(cur ^ 1, cc + 1);   // async, drained by barrier

        f32x16 acc0, acc1;                                  // dual chains (dep-latency)
        #pragma unroll
        for (int j = 0; j < 16; ++j) { acc0[j] = 0.f; acc1[j] = 0.f; }

        const char* bb = bufB + cur * 32768;
        bf16x8 A_[2], B_[2];
        A_[0] = *(const bf16x8*)(bufA + aoff + qa);
        B_[0] = *(const bf16x8*)(bb   + boff + qa);
        #pragma unroll
        for (int s = 0; s < 16; ++s) {
            if (s < 15) {
                int ko = ((s + 1) * 32) ^ qa;
                A_[(s + 1) & 1] = *(const bf16x8*)(bufA + aoff + ko);
                B_[(s + 1) & 1] = *(const bf16x8*)(bb   + boff + ko);
            }
            if (s & 1)
                acc1 = __builtin_amdgcn_mfma_f32_32x32x16_bf16(A_[1], B_[1], acc1, 0, 0, 0);
            else
                acc0 = __builtin_amdgcn_mfma_f32_32x32x16_bf16(A_[0], B_[0], acc0, 0, 0, 0);
        }

        // fold t = sq_row - 2c ; C/D row = (reg&3) + 8*(reg>>2) + 4*hh (within rg tile)
        float m_run = init;
        #pragma unroll
        for (int rq = 0; rq < 4; ++rq) {
            f32x4 s4 = *(const f32x4*)(sq_lds + rg * 32 + 4 * hh + 8 * rq);
            #pragma unroll
            for (int j = 0; j < 4; ++j) {
                float t = s4[j] - 2.0f * (acc0[rq * 4 + j] + acc1[rq * 4 + j]);
                m_run = minmode ? fminf(m_run, t) : fmaxf(m_run, t);
            }
        }
        float o = __shfl_xor(m_run, 32);            // other 4-row half, same col
        m_run = minmode ? fminf(m_run, o) : fmaxf(m_run, o);
        if (lane < 32) pbuf[(cc & 1) * 256 + rg * 64 + cg * 32 + l31] = m_run;

        __syncthreads();   // B chunk cc+1 staged; pbuf published

        if (w == 0) {      // cross-rowgroup reduce + g_part write (64 cols)
            const float* pb = pbuf + (cc & 1) * 256;
            float a0 = pb[lane], a1 = pb[64 + lane], a2 = pb[128 + lane], a3 = pb[192 + lane];
            float m = minmode ? fminf(fminf(a0, a1), fminf(a2, a3))
                              : fmaxf(fmaxf(a0, a1), fmaxf(a2, a3));
            g_part[(size_t)rowblk * NROWS + colsplit * COLS_PER_SPLIT + cc * CCW + lane] = m;
        }
        cur ^= 1;
    }
#undef STAGE_B
}

// ---------------- Kernel 3: per-column reduce over 64 partials ----------------
__global__ __launch_bounds__(256) void finish1_kernel() {
    int col = blockIdx.x * 256 + threadIdx.x;        // grid 64 -> 16384 cols
    bool mn = col >= NHALF;
    float m = mn ? 3.0e38f : -3.0e38f;
    for (int p = 0; p < NROWBLK; ++p) {
        float v = g_part[(size_t)p * NROWS + col];   // coalesced across threads
        m = mn ? fminf(m, v) : fmaxf(m, v);
    }
    float d = sqrtf(fmaxf(m + g_sq[col], 0.f));
    g_colres[col] = mn ? fmaxf(TMARGIN - d, 0.f) : d;
}

// ---------------- Kernel 4: sum columns, scalar out ----------------
__global__ __launch_bounds__(256) void finish2_kernel(float* __restrict__ out) {
    int tid = threadIdx.x;
    float s1 = 0.f, s2 = 0.f;
    for (int j = tid; j < NROWS; j += 256) {
        float v = g_colres[j];
        if (j < NHALF) s1 += v; else s2 += v;
    }
    #pragma unroll
    for (int off = 32; off > 0; off >>= 1) {
        s1 += __shfl_xor(s1, off);
        s2 += __shfl_xor(s2, off);
    }
    __shared__ float r1[4], r2[4];
    int w = tid >> 6, lane = tid & 63;
    if (lane == 0) { r1[w] = s1; r2[w] = s2; }
    __syncthreads();
    if (tid == 0) {
        float a = r1[0] + r1[1] + r1[2] + r1[3];
        float b = r2[0] + r2[1] + r2[2] + r2[3];
        out[0] = a / (float)NHALF + b / (float)NHALF;
    }
}

extern "C" void kernel_launch(void* const* d_in, const int* in_sizes, int n_in,
                              void* d_out, int out_size, void* d_ws, size_t ws_size,
                              hipStream_t stream) {
    const float* feats = (const float*)d_in[0];
    float* out = (float*)d_out;
    hipLaunchKernelGGL(prep_kernel,    dim3(NROWS / 4),           dim3(256), 0, stream, feats);
    hipLaunchKernelGGL(dist_kernel,    dim3(NROWBLK * NCOLSPLIT), dim3(512), 0, stream);
    hipLaunchKernelGGL(finish1_kernel, dim3(NROWS / 256),         dim3(256), 0, stream);
    hipLaunchKernelGGL(finish2_kernel, dim3(1),                   dim3(256), 0, stream, out);
}